// Round 5
// baseline (391.052 us; speedup 1.0000x reference)
//
#include <hip/hip_runtime.h>
#include <cstdint>
#include <cstddef>

#define EPSV 1e-5f
constexpr int B_ = 8;
constexpr int C_ = 512;
constexpr int N_ = 2048;

typedef _Float16 f16x8 __attribute__((ext_vector_type(8)));
typedef float    f32x4 __attribute__((ext_vector_type(4)));

__device__ __forceinline__ unsigned short f16b(float f) {
    _Float16 h = (_Float16)f;
    return __builtin_bit_cast(unsigned short, h);
}

__device__ __forceinline__ void gload_lds16(const void* g, void* l) {
    __builtin_amdgcn_global_load_lds(
        (const __attribute__((address_space(1))) void*)g,
        (__attribute__((address_space(3))) void*)l, 16, 0, 0);
}

// ---------------------------------------------------------------------------
// x (B,C,N) fp32 -> xT (B,N,C) fp16 (transposed so all GEMMs are K-contig)
// ---------------------------------------------------------------------------
__global__ __launch_bounds__(256) void split_x_kernel(
    const float* __restrict__ x, unsigned short* __restrict__ xh)
{
    __shared__ float T[64][65];
    const int b = blockIdx.z, c0 = blockIdx.y * 64, n0 = blockIdx.x * 64;
    const float* xb = x + ((size_t)b * C_ + c0) * N_ + n0;
    const int tid = threadIdx.x;
    const int lr = tid >> 4;
    const int lcn = (tid & 15) * 4;
#pragma unroll
    for (int it = 0; it < 4; ++it) {
        float4 v = *(const float4*)&xb[(size_t)(lr + 16 * it) * N_ + lcn];
        T[lr + 16 * it][lcn + 0] = v.x;
        T[lr + 16 * it][lcn + 1] = v.y;
        T[lr + 16 * it][lcn + 2] = v.z;
        T[lr + 16 * it][lcn + 3] = v.w;
    }
    __syncthreads();
    const int n = tid >> 2, cb = (tid & 3) * 16;
    alignas(16) unsigned short h[16];
#pragma unroll
    for (int i = 0; i < 16; ++i)
        h[i] = f16b(T[cb + i][n]);
    const size_t o = ((size_t)b * N_ + n0 + n) * C_ + c0 + cb;
    *(uint4*)&xh[o]     = *(uint4*)&h[0];
    *(uint4*)&xh[o + 8] = *(uint4*)&h[8];
}

// ---------------------------------------------------------------------------
// W (512x512) fp32 -> fp16
// ---------------------------------------------------------------------------
__global__ __launch_bounds__(256) void split_w_kernel(
    const float* __restrict__ W, unsigned short* __restrict__ wh)
{
    const int i = (blockIdx.x * 256 + threadIdx.x) * 4;
    float4 v = *(const float4*)&W[i];
    alignas(8) unsigned short h[4];
    h[0] = f16b(v.x); h[1] = f16b(v.y); h[2] = f16b(v.z); h[3] = f16b(v.w);
    *(ushort4*)&wh[i] = *(ushort4*)&h[0];
}

// ---------------------------------------------------------------------------
// MFMA GEMM (fp16 in, fp32 acc): C = A * B^T.  m97 structure, 128x128 tile.
// EPI_QK additionally reduces per-row partial softmax stats over this block's
// 128-col slice (per 64-col wave half) into ML:
//   ML[((b*32 + bx*2 + wc)*2 + {0:m,1:l})*2048 + row]
// ---------------------------------------------------------------------------
constexpr int EPI_QK = 0, EPI_PROJT = 2, EPI_PROJV = 3;

template <int EPI>
__global__ __launch_bounds__(256) void gemm_mfma(
    const unsigned short* __restrict__ Ah, const unsigned short* __restrict__ Bh,
    int M, int N, int K, int lda, int ldb,
    long strideA, long strideB, long strideC,
    void* __restrict__ C0, float* __restrict__ ML,
    const float* __restrict__ g, const float* __restrict__ bt,
    const float* __restrict__ mu, const float* __restrict__ var)
{
    __shared__ char smem[16384];   // A: [0,8K), B: [8K,16K)

    const int bz = blockIdx.z;
    const unsigned short* Ahb = Ah + (size_t)bz * strideA;
    const unsigned short* Bhb = Bh + (size_t)bz * strideB;

    const int n0 = blockIdx.x * 128;
    const int m0 = blockIdx.y * 128;

    const int tid = threadIdx.x;
    const int lane = tid & 63;
    const int wv = tid >> 6;
    const int wr = wv >> 1, wc = wv & 1;
    const int l4 = lane >> 4, l15 = lane & 15;
    const int srow = lane >> 2, scol8 = (lane & 3) * 8;

    f32x4 acc[4][4] = {};

    for (int k0 = 0; k0 < K; k0 += 32) {
#pragma unroll
        for (int cc = 0; cc < 2; ++cc) {
            const int c = wv * 2 + cc;
            const size_t aoff = (size_t)(m0 + c * 16 + srow) * lda + k0 + scol8;
            const size_t boff = (size_t)(n0 + c * 16 + srow) * ldb + k0 + scol8;
            gload_lds16(Ahb + aoff, smem + c * 1024);
            gload_lds16(Bhb + boff, smem + 8192 + c * 1024);
        }
        __syncthreads();

        f16x8 ah[4], bh[4];
#pragma unroll
        for (int f = 0; f < 4; ++f) {
            const int arow = wr * 64 + f * 16 + l15;
            const int brow = wc * 64 + f * 16 + l15;
            ah[f] = *(const f16x8*)(smem + arow * 64 + l4 * 16);
            bh[f] = *(const f16x8*)(smem + 8192 + brow * 64 + l4 * 16);
        }
#pragma unroll
        for (int fm = 0; fm < 4; ++fm)
#pragma unroll
            for (int fn = 0; fn < 4; ++fn)
                acc[fm][fn] = __builtin_amdgcn_mfma_f32_16x16x32_f16(
                    ah[fm], bh[fn], acc[fm][fn], 0, 0, 0);
        __syncthreads();
    }

#pragma unroll
    for (int fm = 0; fm < 4; ++fm) {
#pragma unroll
        for (int fn = 0; fn < 4; ++fn) {
            const int m = m0 + wr * 64 + fm * 16 + l4 * 4;
            const int n = n0 + wc * 64 + fn * 16 + l15;
            if constexpr (EPI == EPI_QK) {
                float* Cb = (float*)C0 + (size_t)bz * strideC;
#pragma unroll
                for (int r = 0; r < 4; ++r)
                    Cb[(size_t)(m + r) * N + n] = acc[fm][fn][r];
            } else if constexpr (EPI == EPI_PROJT) {
                unsigned short* H = (unsigned short*)C0 + (size_t)bz * strideC;
                alignas(8) unsigned short h4[4];
#pragma unroll
                for (int r = 0; r < 4; ++r) {
                    const int o = m + r;
                    const float sc = g[o] * rsqrtf(var[o] + EPSV);
                    const float sh = bt[o] - mu[o] * sc;
                    h4[r] = f16b(acc[fm][fn][r] * sc + sh);
                }
                *(ushort4*)&H[(size_t)n * M + m] = *(ushort4*)&h4[0];
            } else {  // EPI_PROJV
                unsigned short* H = (unsigned short*)C0 + (size_t)bz * strideC;
                const float sc = g[n] * rsqrtf(var[n] + EPSV);
                const float sh = bt[n] - mu[n] * sc;
                alignas(8) unsigned short h4[4];
#pragma unroll
                for (int r = 0; r < 4; ++r)
                    h4[r] = f16b(acc[fm][fn][r] * sc + sh);
                *(ushort4*)&H[(size_t)n * M + m] = *(ushort4*)&h4[0];
            }
        }
    }

    if constexpr (EPI == EPI_QK) {
        // per-row partial (max, sumexp) over this wave's 64-col slice
        const size_t mbase =
            (((size_t)bz * 32 + blockIdx.x * 2 + wc) * 2) * 2048;
#pragma unroll
        for (int fm = 0; fm < 4; ++fm) {
#pragma unroll
            for (int r = 0; r < 4; ++r) {
                float mx = fmaxf(fmaxf(acc[fm][0][r], acc[fm][1][r]),
                                 fmaxf(acc[fm][2][r], acc[fm][3][r]));
#pragma unroll
                for (int off = 1; off < 16; off <<= 1)
                    mx = fmaxf(mx, __shfl_xor(mx, off));
                float s = __expf(acc[fm][0][r] - mx) + __expf(acc[fm][1][r] - mx)
                        + __expf(acc[fm][2][r] - mx) + __expf(acc[fm][3][r] - mx);
#pragma unroll
                for (int off = 1; off < 16; off <<= 1)
                    s += __shfl_xor(s, off);
                if (l15 == 0) {
                    const int row = m0 + wr * 64 + fm * 16 + l4 * 4 + r;
                    ML[mbase + row] = mx;
                    ML[mbase + 2048 + row] = s;
                }
            }
        }
    }
}

// ---------------------------------------------------------------------------
// Combine 32 per-tile (m,l) partials into final m[i] and 1/l[i] per row.
// One thread per (b, i).
// ---------------------------------------------------------------------------
__global__ __launch_bounds__(256) void ml_combine_kernel(
    const float* __restrict__ ml, float* __restrict__ mfin,
    float* __restrict__ linv)
{
    const int idx = blockIdx.x * 256 + threadIdx.x;   // b*2048 + i
    const int b = idx >> 11, i = idx & 2047;
    const float* base = ml + ((size_t)b * 32) * 2 * 2048 + i;
    float M = -3.0e38f;
#pragma unroll 8
    for (int t = 0; t < 32; ++t)
        M = fmaxf(M, base[(size_t)t * 4096]);
    float L = 0.f;
#pragma unroll 8
    for (int t = 0; t < 32; ++t)
        L += __expf(base[(size_t)t * 4096] - M) * base[(size_t)t * 4096 + 2048];
    mfin[idx] = M;
    linv[idx] = 1.0f / L;
}

// ---------------------------------------------------------------------------
// PV with on-the-fly exp: out[b,d,i] = (sum_j exp(w[i,j]-m[i]) * v[d,j]) / l[i]
// as O^T = v * P^T via MFMA.  No shfl/rescale in the loop (m,l precomputed).
// QBLK=32 i-rows per block; 8 waves split D (64 each); no LDS, no barriers.
// Register-double-buffered (named bufs, rule #20).
// ---------------------------------------------------------------------------
struct PvB {
    float4 w0[2], w1[2];   // per nt: 8 fp32 of w
    uint4  vv[4];          // per mt: 8 fp16 of v
};

__global__ __launch_bounds__(512, 4) void pv_exp_kernel(
    const float* __restrict__ w, const unsigned short* __restrict__ v,
    const float* __restrict__ mfin, const float* __restrict__ linv,
    float* __restrict__ out)
{
    const int b  = blockIdx.y;
    const int i0 = blockIdx.x * 32;
    const float* wb = w + (size_t)b * N_ * N_;
    const unsigned short* vb = v + (size_t)b * C_ * N_;   // (d, j) j-contig
    float* ob = out + (size_t)b * C_ * N_;

    const int tid  = threadIdx.x;
    const int lane = tid & 63;
    const int wv   = tid >> 6;            // 0..7, D-slice owner
    const int l4   = lane >> 4, l15 = lane & 15;
    const int dOff = wv * 64;

    const float* wrow[2];
#pragma unroll
    for (int nt = 0; nt < 2; ++nt)
        wrow[nt] = wb + (size_t)(i0 + nt * 16 + l15) * N_ + l4 * 8;
    const unsigned short* vrow[4];
#pragma unroll
    for (int mt = 0; mt < 4; ++mt)
        vrow[mt] = vb + (size_t)(dOff + mt * 16 + l15) * N_ + l4 * 8;

    const float mi0 = mfin[b * 2048 + i0 + l15];
    const float mi1 = mfin[b * 2048 + i0 + 16 + l15];

    f32x4 acc[4][2] = {};                 // [mt][nt]

#define PV_LOAD(buf, js)                                                     \
    {                                                                        \
        const int j32 = (js) * 32;                                           \
        _Pragma("unroll")                                                    \
        for (int nt = 0; nt < 2; ++nt) {                                     \
            buf.w0[nt] = *(const float4*)(wrow[nt] + j32);                   \
            buf.w1[nt] = *(const float4*)(wrow[nt] + j32 + 4);               \
        }                                                                    \
        _Pragma("unroll")                                                    \
        for (int mt = 0; mt < 4; ++mt)                                       \
            buf.vv[mt] = *(const uint4*)(vrow[mt] + j32);                    \
    }

#define PV_PROC(buf)                                                         \
    {                                                                        \
        _Pragma("unroll")                                                    \
        for (int nt = 0; nt < 2; ++nt) {                                     \
            const float mi = nt ? mi1 : mi0;                                 \
            const float* wp0 = (const float*)&buf.w0[nt];                    \
            const float* wp1 = (const float*)&buf.w1[nt];                    \
            f16x8 pf;                                                        \
            _Pragma("unroll")                                                \
            for (int e = 0; e < 4; ++e)                                      \
                pf[e] = (_Float16)__expf(wp0[e] - mi);                       \
            _Pragma("unroll")                                                \
            for (int e = 0; e < 4; ++e)                                      \
                pf[4 + e] = (_Float16)__expf(wp1[e] - mi);                   \
            _Pragma("unroll")                                                \
            for (int mt = 0; mt < 4; ++mt)                                   \
                acc[mt][nt] = __builtin_amdgcn_mfma_f32_16x16x32_f16(        \
                    *(const f16x8*)&buf.vv[mt], pf, acc[mt][nt], 0, 0, 0);   \
        }                                                                    \
    }

    PvB bufA, bufB;
    PV_LOAD(bufA, 0);
    for (int js = 0; js < 64; js += 2) {
        PV_LOAD(bufB, js + 1);
        PV_PROC(bufA);
        const int jn = (js + 2 < 64) ? js + 2 : 63;
        PV_LOAD(bufA, jn);
        PV_PROC(bufB);
    }

    const float li0 = linv[b * 2048 + i0 + l15];
    const float li1 = linv[b * 2048 + i0 + 16 + l15];
#pragma unroll
    for (int mt = 0; mt < 4; ++mt)
#pragma unroll
        for (int nt = 0; nt < 2; ++nt) {
            const int i = i0 + nt * 16 + l15;
            const float li = nt ? li1 : li0;
#pragma unroll
            for (int r = 0; r < 4; ++r) {
                const int d = dOff + mt * 16 + l4 * 4 + r;
                ob[(size_t)d * N_ + i] = acc[mt][nt][r] * li;
            }
        }
#undef PV_LOAD
#undef PV_PROC
}

// ---------------------------------------------------------------------------
extern "C" void kernel_launch(void* const* d_in, const int* in_sizes, int n_in,
                              void* d_out, int out_size, void* d_ws, size_t ws_size,
                              hipStream_t stream)
{
    (void)in_sizes; (void)n_in; (void)out_size; (void)ws_size;
    const float* x  = (const float*)d_in[0];
    const float* Wq = (const float*)d_in[1];
    const float* gq = (const float*)d_in[2];
    const float* bq = (const float*)d_in[3];
    const float* mq = (const float*)d_in[4];
    const float* vq = (const float*)d_in[5];
    const float* Wk = (const float*)d_in[6];
    const float* gk = (const float*)d_in[7];
    const float* bk = (const float*)d_in[8];
    const float* mk = (const float*)d_in[9];
    const float* vk = (const float*)d_in[10];
    const float* Wv = (const float*)d_in[11];
    const float* gv = (const float*)d_in[12];
    const float* bv = (const float*)d_in[13];
    const float* mv = (const float*)d_in[14];
    const float* vv = (const float*)d_in[15];
    float* out = (float*)d_out;

    const size_t MiB = 1048576;
    char* ws = (char*)d_ws;
    unsigned short* Wqh = (unsigned short*)(ws + 0 * 524288);
    unsigned short* Wkh = (unsigned short*)(ws + 1 * 524288);
    unsigned short* Wvh = (unsigned short*)(ws + 2 * 524288);
    unsigned short* vbf = (unsigned short*)(ws + 2 * MiB);    // 16 MiB (C,N)
    unsigned short* qTh = (unsigned short*)(ws + 18 * MiB);   // 16 MiB (N,C)
    unsigned short* kTh = (unsigned short*)(ws + 34 * MiB);   // 16 MiB (N,C)
    unsigned short* xTh = (unsigned short*)(ws + 50 * MiB);   // 16 MiB (N,C)
    float* wbuf  = (float*)(ws + 66 * MiB);                   // 128 MiB fp32
    float* mlbuf = (float*)(ws + 194 * MiB);                  // 4 MiB partials
    float* mfin  = (float*)(ws + 198 * MiB);                  // 64 KiB
    float* linv  = (float*)(ws + 198 * MiB + 65536);          // 64 KiB

    const long BS = (long)N_ * C_;  // elems per batch

    // --- fp16 conversions ---
    split_x_kernel<<<dim3(N_ / 64, C_ / 64, B_), 256, 0, stream>>>(x, xTh);
    split_w_kernel<<<dim3(256), 256, 0, stream>>>(Wq, Wqh);
    split_w_kernel<<<dim3(256), 256, 0, stream>>>(Wk, Wkh);
    split_w_kernel<<<dim3(256), 256, 0, stream>>>(Wv, Wvh);

    // --- projections ---
    gemm_mfma<EPI_PROJT><<<dim3(16, 4, B_), 256, 0, stream>>>(
        Wqh, xTh, 512, 2048, 512, 512, 512, 0, BS, BS, qTh, nullptr,
        gq, bq, mq, vq);
    gemm_mfma<EPI_PROJT><<<dim3(16, 4, B_), 256, 0, stream>>>(
        Wkh, xTh, 512, 2048, 512, 512, 512, 0, BS, BS, kTh, nullptr,
        gk, bk, mk, vk);
    gemm_mfma<EPI_PROJV><<<dim3(4, 16, B_), 256, 0, stream>>>(
        xTh, Wvh, 2048, 512, 512, 512, 512, BS, 0, BS, vbf, nullptr,
        gv, bv, mv, vv);

    // --- logits + per-tile softmax stats ---
    gemm_mfma<EPI_QK><<<dim3(16, 16, B_), 256, 0, stream>>>(
        qTh, kTh, 2048, 2048, 512, 512, 512, BS, BS, (long)N_ * N_, wbuf,
        mlbuf, nullptr, nullptr, nullptr, nullptr);

    // --- combine stats ---
    ml_combine_kernel<<<dim3(B_ * N_ / 256), 256, 0, stream>>>(
        mlbuf, mfin, linv);

    // --- PV with on-the-fly exp ---
    pv_exp_kernel<<<dim3(N_ / 32, B_), 512, 0, stream>>>(
        wbuf, vbf, mfin, linv, out);
}

// Round 6
// 240.137 us; speedup vs baseline: 1.6285x; 1.6285x over previous
//
#include <hip/hip_runtime.h>
#include <cstdint>
#include <cstddef>

#define EPSV 1e-5f
constexpr int B_ = 8;
constexpr int C_ = 512;
constexpr int N_ = 2048;

typedef _Float16 f16x8 __attribute__((ext_vector_type(8)));
typedef float    f32x4 __attribute__((ext_vector_type(4)));

__device__ __forceinline__ unsigned short f16b(float f) {
    _Float16 h = (_Float16)f;
    return __builtin_bit_cast(unsigned short, h);
}

__device__ __forceinline__ void gload_lds16(const void* g, void* l) {
    __builtin_amdgcn_global_load_lds(
        (const __attribute__((address_space(1))) void*)g,
        (__attribute__((address_space(3))) void*)l, 16, 0, 0);
}

// ---------------------------------------------------------------------------
// x (B,C,N) fp32 -> xT (B,N,C) fp16 (transposed so all GEMMs are K-contig)
// ---------------------------------------------------------------------------
__global__ __launch_bounds__(256) void split_x_kernel(
    const float* __restrict__ x, unsigned short* __restrict__ xh)
{
    __shared__ float T[64][65];
    const int b = blockIdx.z, c0 = blockIdx.y * 64, n0 = blockIdx.x * 64;
    const float* xb = x + ((size_t)b * C_ + c0) * N_ + n0;
    const int tid = threadIdx.x;
    const int lr = tid >> 4;
    const int lcn = (tid & 15) * 4;
#pragma unroll
    for (int it = 0; it < 4; ++it) {
        float4 v = *(const float4*)&xb[(size_t)(lr + 16 * it) * N_ + lcn];
        T[lr + 16 * it][lcn + 0] = v.x;
        T[lr + 16 * it][lcn + 1] = v.y;
        T[lr + 16 * it][lcn + 2] = v.z;
        T[lr + 16 * it][lcn + 3] = v.w;
    }
    __syncthreads();
    const int n = tid >> 2, cb = (tid & 3) * 16;
    alignas(16) unsigned short h[16];
#pragma unroll
    for (int i = 0; i < 16; ++i)
        h[i] = f16b(T[cb + i][n]);
    const size_t o = ((size_t)b * N_ + n0 + n) * C_ + c0 + cb;
    *(uint4*)&xh[o]     = *(uint4*)&h[0];
    *(uint4*)&xh[o + 8] = *(uint4*)&h[8];
}

// ---------------------------------------------------------------------------
// W (512x512) fp32 -> fp16
// ---------------------------------------------------------------------------
__global__ __launch_bounds__(256) void split_w_kernel(
    const float* __restrict__ W, unsigned short* __restrict__ wh)
{
    const int i = (blockIdx.x * 256 + threadIdx.x) * 4;
    float4 v = *(const float4*)&W[i];
    alignas(8) unsigned short h[4];
    h[0] = f16b(v.x); h[1] = f16b(v.y); h[2] = f16b(v.z); h[3] = f16b(v.w);
    *(ushort4*)&wh[i] = *(ushort4*)&h[0];
}

// ---------------------------------------------------------------------------
// MFMA GEMM (fp16 in, fp32 acc): C = A * B^T.  m97 structure, 128x128 tile.
// EPI_QK:   writes p_local = exp(w - m_tile) fp16 to C0 and per-64-col-tile
//           stats (m_t, l_t) to ML[((bz*32 + bx*2 + wc)*2)*2048 + {0,+2048}+row]
// EPI_PV:   A-fragments scaled by corr[b,t,i] (t = k0/64), epilogue * linv[i];
//           fp32 out at [n*M+m] (d-major)
// EPI_PROJT/PROJV: fused BN, fp16 out at [n*M+m]
// ---------------------------------------------------------------------------
constexpr int EPI_QK = 0, EPI_PV = 1, EPI_PROJT = 2, EPI_PROJV = 3;

template <int EPI>
__global__ __launch_bounds__(256) void gemm_mfma(
    const unsigned short* __restrict__ Ah, const unsigned short* __restrict__ Bh,
    int M, int N, int K, int lda, int ldb,
    long strideA, long strideB, long strideC,
    void* __restrict__ C0, float* __restrict__ ML,
    const float* __restrict__ corr, const float* __restrict__ linv,
    const float* __restrict__ g, const float* __restrict__ bt,
    const float* __restrict__ mu, const float* __restrict__ var)
{
    __shared__ char smem[16384];   // A: [0,8K), B: [8K,16K)

    const int bz = blockIdx.z;
    const unsigned short* Ahb = Ah + (size_t)bz * strideA;
    const unsigned short* Bhb = Bh + (size_t)bz * strideB;

    const int n0 = blockIdx.x * 128;
    const int m0 = blockIdx.y * 128;

    const int tid = threadIdx.x;
    const int lane = tid & 63;
    const int wv = tid >> 6;
    const int wr = wv >> 1, wc = wv & 1;
    const int l4 = lane >> 4, l15 = lane & 15;
    const int srow = lane >> 2, scol8 = (lane & 3) * 8;

    f32x4 acc[4][4] = {};
    float ca[4];                       // EPI_PV: per-fm corr for current tile

    for (int k0 = 0; k0 < K; k0 += 32) {
        if constexpr (EPI == EPI_PV) {
            if ((k0 & 63) == 0) {
                const int t = k0 >> 6;
                const float* cb = corr + ((size_t)bz * 32 + t) * 2048 + m0;
#pragma unroll
                for (int f = 0; f < 4; ++f)
                    ca[f] = cb[wr * 64 + f * 16 + l15];
            }
        }
#pragma unroll
        for (int cc = 0; cc < 2; ++cc) {
            const int c = wv * 2 + cc;
            const size_t aoff = (size_t)(m0 + c * 16 + srow) * lda + k0 + scol8;
            const size_t boff = (size_t)(n0 + c * 16 + srow) * ldb + k0 + scol8;
            gload_lds16(Ahb + aoff, smem + c * 1024);
            gload_lds16(Bhb + boff, smem + 8192 + c * 1024);
        }
        __syncthreads();

        f16x8 ah[4], bh[4];
#pragma unroll
        for (int f = 0; f < 4; ++f) {
            const int arow = wr * 64 + f * 16 + l15;
            const int brow = wc * 64 + f * 16 + l15;
            ah[f] = *(const f16x8*)(smem + arow * 64 + l4 * 16);
            bh[f] = *(const f16x8*)(smem + 8192 + brow * 64 + l4 * 16);
        }
        if constexpr (EPI == EPI_PV) {
#pragma unroll
            for (int f = 0; f < 4; ++f) {
                const _Float16 cf = (_Float16)ca[f];
#pragma unroll
                for (int e = 0; e < 8; ++e)
                    ah[f][e] = ah[f][e] * cf;
            }
        }
#pragma unroll
        for (int fm = 0; fm < 4; ++fm)
#pragma unroll
            for (int fn = 0; fn < 4; ++fn)
                acc[fm][fn] = __builtin_amdgcn_mfma_f32_16x16x32_f16(
                    ah[fm], bh[fn], acc[fm][fn], 0, 0, 0);
        __syncthreads();
    }

    if constexpr (EPI == EPI_QK) {
        // p_local = exp(w - m_tile) fp16; per-row 64-col tile stats (m_t, l_t)
        unsigned short* H = (unsigned short*)C0 + (size_t)bz * strideC;
        const size_t mbase =
            (((size_t)bz * 32 + blockIdx.x * 2 + wc) * 2) * 2048;
#pragma unroll
        for (int fm = 0; fm < 4; ++fm) {
#pragma unroll
            for (int r = 0; r < 4; ++r) {
                float mx = fmaxf(fmaxf(acc[fm][0][r], acc[fm][1][r]),
                                 fmaxf(acc[fm][2][r], acc[fm][3][r]));
#pragma unroll
                for (int off = 1; off < 16; off <<= 1)
                    mx = fmaxf(mx, __shfl_xor(mx, off));
                float pe[4];
                float s = 0.f;
#pragma unroll
                for (int fn = 0; fn < 4; ++fn) {
                    pe[fn] = __expf(acc[fm][fn][r] - mx);
                    s += pe[fn];
                }
#pragma unroll
                for (int off = 1; off < 16; off <<= 1)
                    s += __shfl_xor(s, off);
                const int row = m0 + wr * 64 + fm * 16 + l4 * 4 + r;
                if (l15 == 0) {
                    ML[mbase + row] = mx;
                    ML[mbase + 2048 + row] = s;
                }
#pragma unroll
                for (int fn = 0; fn < 4; ++fn) {
                    const int n = n0 + wc * 64 + fn * 16 + l15;
                    H[(size_t)row * N + n] = f16b(pe[fn]);
                }
            }
        }
    } else if constexpr (EPI == EPI_PV) {
        float* Cb = (float*)C0 + (size_t)bz * strideC;
        const float* lb = linv + (size_t)bz * 2048;
        float lv[4][4];
#pragma unroll
        for (int fm = 0; fm < 4; ++fm)
#pragma unroll
            for (int r = 0; r < 4; ++r)
                lv[fm][r] = lb[m0 + wr * 64 + fm * 16 + l4 * 4 + r];
#pragma unroll
        for (int fm = 0; fm < 4; ++fm)
#pragma unroll
            for (int fn = 0; fn < 4; ++fn) {
                const int m = m0 + wr * 64 + fm * 16 + l4 * 4;
                const int n = n0 + wc * 64 + fn * 16 + l15;
                float4 o4 = make_float4(acc[fm][fn][0] * lv[fm][0],
                                        acc[fm][fn][1] * lv[fm][1],
                                        acc[fm][fn][2] * lv[fm][2],
                                        acc[fm][fn][3] * lv[fm][3]);
                *(float4*)&Cb[(size_t)n * M + m] = o4;
            }
    } else {
#pragma unroll
        for (int fm = 0; fm < 4; ++fm) {
#pragma unroll
            for (int fn = 0; fn < 4; ++fn) {
                const int m = m0 + wr * 64 + fm * 16 + l4 * 4;
                const int n = n0 + wc * 64 + fn * 16 + l15;
                unsigned short* H = (unsigned short*)C0 + (size_t)bz * strideC;
                alignas(8) unsigned short h4[4];
                if constexpr (EPI == EPI_PROJT) {
#pragma unroll
                    for (int r = 0; r < 4; ++r) {
                        const int o = m + r;
                        const float sc = g[o] * rsqrtf(var[o] + EPSV);
                        const float sh = bt[o] - mu[o] * sc;
                        h4[r] = f16b(acc[fm][fn][r] * sc + sh);
                    }
                } else {  // EPI_PROJV
                    const float sc = g[n] * rsqrtf(var[n] + EPSV);
                    const float sh = bt[n] - mu[n] * sc;
#pragma unroll
                    for (int r = 0; r < 4; ++r)
                        h4[r] = f16b(acc[fm][fn][r] * sc + sh);
                }
                *(ushort4*)&H[(size_t)n * M + m] = *(ushort4*)&h4[0];
            }
        }
    }
}

// ---------------------------------------------------------------------------
// Combine 32 per-tile (m,l) partials: m_global, linv = 1/l_global, and
// corr[b,t,i] = exp(m_t - m_global).  One thread per (b, i).
// ---------------------------------------------------------------------------
__global__ __launch_bounds__(256) void ml_combine_kernel(
    const float* __restrict__ ml, float* __restrict__ corr,
    float* __restrict__ linv)
{
    const int idx = blockIdx.x * 256 + threadIdx.x;   // b*2048 + i
    const int b = idx >> 11, i = idx & 2047;
    const float* base = ml + ((size_t)b * 32) * 2 * 2048 + i;
    float M = -3.0e38f;
#pragma unroll 8
    for (int t = 0; t < 32; ++t)
        M = fmaxf(M, base[(size_t)t * 4096]);
    float L = 0.f;
    float* cb = corr + (size_t)b * 32 * 2048 + i;
#pragma unroll 8
    for (int t = 0; t < 32; ++t) {
        const float c = __expf(base[(size_t)t * 4096] - M);
        L += c * base[(size_t)t * 4096 + 2048];
        cb[(size_t)t * 2048] = c;
    }
    linv[idx] = 1.0f / L;
}

// ---------------------------------------------------------------------------
extern "C" void kernel_launch(void* const* d_in, const int* in_sizes, int n_in,
                              void* d_out, int out_size, void* d_ws, size_t ws_size,
                              hipStream_t stream)
{
    (void)in_sizes; (void)n_in; (void)out_size; (void)ws_size;
    const float* x  = (const float*)d_in[0];
    const float* Wq = (const float*)d_in[1];
    const float* gq = (const float*)d_in[2];
    const float* bq = (const float*)d_in[3];
    const float* mq = (const float*)d_in[4];
    const float* vq = (const float*)d_in[5];
    const float* Wk = (const float*)d_in[6];
    const float* gk = (const float*)d_in[7];
    const float* bk = (const float*)d_in[8];
    const float* mk = (const float*)d_in[9];
    const float* vk = (const float*)d_in[10];
    const float* Wv = (const float*)d_in[11];
    const float* gv = (const float*)d_in[12];
    const float* bv = (const float*)d_in[13];
    const float* mv = (const float*)d_in[14];
    const float* vv = (const float*)d_in[15];
    float* out = (float*)d_out;

    const size_t MiB = 1048576;
    char* ws = (char*)d_ws;
    unsigned short* Wqh = (unsigned short*)(ws + 0 * 524288);
    unsigned short* Wkh = (unsigned short*)(ws + 1 * 524288);
    unsigned short* Wvh = (unsigned short*)(ws + 2 * 524288);
    unsigned short* vbf = (unsigned short*)(ws + 2 * MiB);    // 16 MiB (C,N)
    unsigned short* qTh = (unsigned short*)(ws + 18 * MiB);   // 16 MiB (N,C)
    unsigned short* kTh = (unsigned short*)(ws + 34 * MiB);   // 16 MiB (N,C)
    unsigned short* xTh = (unsigned short*)(ws + 50 * MiB);   // 16 MiB (N,C)
    unsigned short* pbuf = (unsigned short*)(ws + 66 * MiB);  // 64 MiB fp16 p
    float* mlbuf = (float*)(ws + 130 * MiB);                  // 4 MiB stats
    float* corr  = (float*)(ws + 134 * MiB);                  // 2 MiB corr
    float* linv  = (float*)(ws + 136 * MiB);                  // 64 KiB

    const long BS = (long)N_ * C_;  // elems per batch

    // --- fp16 conversions ---
    split_x_kernel<<<dim3(N_ / 64, C_ / 64, B_), 256, 0, stream>>>(x, xTh);
    split_w_kernel<<<dim3(256), 256, 0, stream>>>(Wq, Wqh);
    split_w_kernel<<<dim3(256), 256, 0, stream>>>(Wk, Wkh);
    split_w_kernel<<<dim3(256), 256, 0, stream>>>(Wv, Wvh);

    // --- projections ---
    gemm_mfma<EPI_PROJT><<<dim3(16, 4, B_), 256, 0, stream>>>(
        Wqh, xTh, 512, 2048, 512, 512, 512, 0, BS, BS, qTh, nullptr,
        nullptr, nullptr, gq, bq, mq, vq);
    gemm_mfma<EPI_PROJT><<<dim3(16, 4, B_), 256, 0, stream>>>(
        Wkh, xTh, 512, 2048, 512, 512, 512, 0, BS, BS, kTh, nullptr,
        nullptr, nullptr, gk, bk, mk, vk);
    gemm_mfma<EPI_PROJV><<<dim3(4, 16, B_), 256, 0, stream>>>(
        xTh, Wvh, 2048, 512, 512, 512, 512, BS, 0, BS, vbf, nullptr,
        nullptr, nullptr, gv, bv, mv, vv);

    // --- logits -> p_local fp16 + per-tile stats ---
    gemm_mfma<EPI_QK><<<dim3(16, 16, B_), 256, 0, stream>>>(
        qTh, kTh, 2048, 2048, 512, 512, 512, BS, BS, (long)N_ * N_, pbuf,
        mlbuf, nullptr, nullptr, nullptr, nullptr, nullptr, nullptr);

    // --- combine stats -> corr, linv ---
    ml_combine_kernel<<<dim3(B_ * N_ / 256), 256, 0, stream>>>(
        mlbuf, corr, linv);

    // --- PV: M=i(2048), N=d(512), K=j(2048); corr-scaled A, /l epilogue ---
    gemm_mfma<EPI_PV><<<dim3(4, 16, B_), 256, 0, stream>>>(
        pbuf, vbf, 2048, 512, 2048, 2048, 2048,
        (long)N_ * N_, BS, BS, out, nullptr, corr, linv,
        nullptr, nullptr, nullptr, nullptr);
}